// Round 13
// baseline (1654.733 us; speedup 1.0000x reference)
//
#include <hip/hip_runtime.h>
#include <cmath>

#define NB 16      // batch
#define SS 400     // source len
#define TT 96      // target len
#define HL 128     // LSTM per dir
#define HH 256     // decoder hidden (2*HL)
#define AA 64      // attn dim
#define VV 30611   // vocab
#define VVP 30720  // vocab padded to 256
#define START_TOK 101
#define NCHUNK 120 // vocab chunks of 256

typedef __attribute__((ext_vector_type(8))) short bf16x8;
typedef __attribute__((ext_vector_type(4))) float f32x4;

// keep a loaded float4 live in VGPRs (forbid rematerialization / load sinking)
#define PIN4(v) asm volatile("" : "+v"((v).x), "+v"((v).y), "+v"((v).z), "+v"((v).w))
// LDS-only barrier: no vmcnt drain (global stores stay in flight)
#define LBAR() asm volatile("s_waitcnt lgkmcnt(0)\n\ts_barrier" ::: "memory")

// ---------- helpers ----------
__device__ __forceinline__ float gload(const float* p) {
  return __hip_atomic_load(p, __ATOMIC_RELAXED, __HIP_MEMORY_SCOPE_AGENT);
}
__device__ __forceinline__ void gstore(float* p, float v) {
  __hip_atomic_store(p, v, __ATOMIC_RELAXED, __HIP_MEMORY_SCOPE_AGENT);
}
__device__ __forceinline__ float sigmf(float x) { return 1.0f / (1.0f + __expf(-x)); }
__device__ __forceinline__ float tanhf_(float x) {
  float xc = fminf(fmaxf(x, -15.0f), 15.0f);
  return 1.0f - 2.0f / (__expf(2.0f * xc) + 1.0f);
}
__device__ __forceinline__ short f2bf(float f) {
  unsigned u = __float_as_uint(f);
  unsigned r = (u + 0x7FFFu + ((u >> 16) & 1u)) >> 16;
  return (short)r;
}
__device__ __forceinline__ float bf2f(unsigned short s) {
  return __uint_as_float(((unsigned)s) << 16);
}
// flag barrier, RELAXED-only protocol (round 8, verified)
__device__ __forceinline__ void flagbar(int* flags, int b, int g, int target) {
  __syncthreads();
  if (threadIdx.x == 0)
    __hip_atomic_store(&flags[b*8 + g], target, __ATOMIC_RELAXED, __HIP_MEMORY_SCOPE_AGENT);
  if (threadIdx.x < 8) {
    while (__hip_atomic_load(&flags[b*8 + threadIdx.x], __ATOMIC_RELAXED, __HIP_MEMORY_SCOPE_AGENT) < target)
      __builtin_amdgcn_s_sleep(1);
  }
  LBAR();
}

// ---------- init: zero flags ----------
__global__ __launch_bounds__(256) void k_init(int* flags) {
  if (threadIdx.x < 128) flags[threadIdx.x] = 0;
}

// ---------- cast LSTM weights to bf16 (predW cast fused into k_encoder) ----------
__global__ __launch_bounds__(256) void k_casts(
    const float* __restrict__ wf, const float* __restrict__ wb,
    const float* __restrict__ dwih,
    short* __restrict__ wfB, short* __restrict__ wbB, short* __restrict__ dwB,
    short* __restrict__ dwCb)
{
  const int stride = gridDim.x * 256;
  const int t0 = blockIdx.x * 256 + threadIdx.x;
  for (int i = t0; i < 512*1024; i += stride) wfB[i] = f2bf(wf[i]);
  for (int i = t0; i < 512*1024; i += stride) wbB[i] = f2bf(wb[i]);
  for (int i = t0; i < 1024*1024; i += stride) {
    int r = i >> 10, k = i & 1023;
    dwB[i] = f2bf(dwih[r*1280 + k]);
  }
  for (int i = t0; i < 1024*256; i += stride) {
    int n = i >> 8, k = i & 255;
    dwCb[i] = f2bf(dwih[n*1280 + 1024 + k]);
  }
}

// ---------- encoder input projection via MFMA ----------
__global__ __launch_bounds__(256) void k_embproj_enc_mfma(
    const float* __restrict__ emb, const int* __restrict__ article,
    const short* __restrict__ wfB, const short* __restrict__ wbB,
    const float* __restrict__ bf, const float* __restrict__ bb,
    float* __restrict__ xcomb)
{
  const int m0 = blockIdx.x * 64;
  const int n0 = blockIdx.y * 256;
  const int t = threadIdx.x;
  const int w = t >> 6, l = t & 63;
  __shared__ short Abuf[64*136];
  __shared__ int tok[64];
  if (t < 64) {
    int R = m0 + t, s = R >> 4, b = R & 15;
    tok[t] = article[b*SS + s];
  }
  const short* __restrict__ Wb = (n0 < 512) ? wfB : wbB;
  const int nb0 = (n0 < 512) ? n0 : (n0 - 512);
  f32x4 acc[4][4];
  #pragma unroll
  for (int i = 0; i < 4; ++i)
    #pragma unroll
    for (int j = 0; j < 4; ++j) acc[i][j] = (f32x4){0.f,0.f,0.f,0.f};
  __syncthreads();
  const int ar = t >> 2, ak0 = (t & 3) * 32;
  for (int kc = 0; kc < 8; ++kc) {
    const float* src = emb + (size_t)tok[ar]*1024 + kc*128 + ak0;
    #pragma unroll
    for (int j = 0; j < 8; ++j) {
      float4 v = *(const float4*)(src + 4*j);
      short4 s4; s4.x = f2bf(v.x); s4.y = f2bf(v.y); s4.z = f2bf(v.z); s4.w = f2bf(v.w);
      *(short4*)(&Abuf[ar*136 + ak0 + 4*j]) = s4;
    }
    LBAR();
    #pragma unroll
    for (int ks = 0; ks < 4; ++ks) {
      bf16x8 af[4];
      #pragma unroll
      for (int mr = 0; mr < 4; ++mr)
        af[mr] = *(const bf16x8*)(&Abuf[(mr*16 + (l & 15))*136 + ks*32 + (l >> 4)*8]);
      #pragma unroll
      for (int ct = 0; ct < 4; ++ct) {
        int n = nb0 + w*64 + ct*16 + (l & 15);
        bf16x8 bfr = *(const bf16x8*)(Wb + (size_t)n*1024 + kc*128 + ks*32 + (l >> 4)*8);
        #pragma unroll
        for (int mr = 0; mr < 4; ++mr)
          acc[mr][ct] = __builtin_amdgcn_mfma_f32_16x16x32_bf16(af[mr], bfr, acc[mr][ct], 0, 0, 0);
      }
    }
    LBAR();
  }
  #pragma unroll
  for (int ct = 0; ct < 4; ++ct) {
    int n = n0 + w*64 + ct*16 + (l & 15);
    float bias = (n < 512) ? bf[n] : bb[n - 512];
    #pragma unroll
    for (int mr = 0; mr < 4; ++mr) {
      #pragma unroll
      for (int r = 0; r < 4; ++r) {
        int R = m0 + mr*16 + (l >> 4)*4 + r;
        xcomb[(size_t)R*1024 + n] = acc[mr][ct][r] + bias;
      }
    }
  }
}

// ---------- decoder embedding projection via MFMA (dec_b folded) ----------
__global__ __launch_bounds__(256) void k_embproj_dec_mfma(
    const float* __restrict__ emb, const int* __restrict__ abstr,
    const short* __restrict__ dwB, const float* __restrict__ db,
    float* __restrict__ decpre)
{
  const int m0 = blockIdx.x * 64;
  const int n0 = blockIdx.y * 256;
  const int t = threadIdx.x;
  const int w = t >> 6, l = t & 63;
  __shared__ short Abuf[64*136];
  __shared__ int tok[64];
  if (t < 64) {
    int R = m0 + t, tt = R >> 4, b = R & 15;
    tok[t] = (tt == 0) ? START_TOK : abstr[b*TT + tt - 1];
  }
  f32x4 acc[4][4];
  #pragma unroll
  for (int i = 0; i < 4; ++i)
    #pragma unroll
    for (int j = 0; j < 4; ++j) acc[i][j] = (f32x4){0.f,0.f,0.f,0.f};
  __syncthreads();
  const int ar = t >> 2, ak0 = (t & 3) * 32;
  for (int kc = 0; kc < 8; ++kc) {
    const float* src = emb + (size_t)tok[ar]*1024 + kc*128 + ak0;
    #pragma unroll
    for (int j = 0; j < 8; ++j) {
      float4 v = *(const float4*)(src + 4*j);
      short4 s4; s4.x = f2bf(v.x); s4.y = f2bf(v.y); s4.z = f2bf(v.z); s4.w = f2bf(v.w);
      *(short4*)(&Abuf[ar*136 + ak0 + 4*j]) = s4;
    }
    LBAR();
    #pragma unroll
    for (int ks = 0; ks < 4; ++ks) {
      bf16x8 af[4];
      #pragma unroll
      for (int mr = 0; mr < 4; ++mr)
        af[mr] = *(const bf16x8*)(&Abuf[(mr*16 + (l & 15))*136 + ks*32 + (l >> 4)*8]);
      #pragma unroll
      for (int ct = 0; ct < 4; ++ct) {
        int n = n0 + w*64 + ct*16 + (l & 15);
        bf16x8 bfr = *(const bf16x8*)(dwB + (size_t)n*1024 + kc*128 + ks*32 + (l >> 4)*8);
        #pragma unroll
        for (int mr = 0; mr < 4; ++mr)
          acc[mr][ct] = __builtin_amdgcn_mfma_f32_16x16x32_bf16(af[mr], bfr, acc[mr][ct], 0, 0, 0);
      }
    }
    LBAR();
  }
  #pragma unroll
  for (int ct = 0; ct < 4; ++ct) {
    int n = n0 + w*64 + ct*16 + (l & 15);
    float bias = db[n];
    #pragma unroll
    for (int mr = 0; mr < 4; ++mr) {
      #pragma unroll
      for (int r = 0; r < 4; ++r) {
        int R = m0 + mr*16 + (l >> 4)*4 + r;
        decpre[(size_t)R*1024 + n] = acc[mr][ct][r] + bias;
      }
    }
  }
}

// ---------- encoder (blocks 0..31) + predW bf16 cast (blocks 32..255, hidden) ----------
__global__ __launch_bounds__(1024, 4) void k_encoder(
    const float* __restrict__ xcomb,
    const float* __restrict__ whhf, const float* __restrict__ whhb,
    float* __restrict__ encout,
    float* __restrict__ hpub,
    float* __restrict__ c0buf,
    const float* __restrict__ predW, short* __restrict__ predWb)
{
  const int t = threadIdx.x;
  if (blockIdx.x >= 32) {
    const size_t idx0 = (size_t)(blockIdx.x - 32) * 1024 + t;
    const size_t stride = (size_t)224 * 1024;
    for (size_t i = idx0; i < (size_t)VVP*256; i += stride)
      predWb[i] = (i < (size_t)VV*256) ? f2bf(predW[i]) : (short)0;
    return;
  }
  const int b = blockIdx.x & 15, dir = blockIdx.x >> 4;
  const int row = t & 511;
  const int ks = t >> 9;
  const float* __restrict__ Whh = dir ? whhb : whhf;
  float4 wr[16];
  #pragma unroll
  for (int j = 0; j < 16; ++j) {
    wr[j] = *(const float4*)(Whh + row*128 + ks*64 + j*4);
    PIN4(wr[j]);
  }
  __shared__ float hl[128];
  __shared__ float part[2][512];
  float c_reg = 0.0f;
  if (t < 128) hl[t] = 0.0f;
  float xv0 = 0.f, xv1 = 0.f, xv2 = 0.f, xv3 = 0.f;
  if (t < 128) {
    const float* xr = xcomb + ((dir ? (SS-1) : 0)*NB + b)*1024 + dir*512 + t;
    xv0 = xr[0]; xv1 = xr[128]; xv2 = xr[256]; xv3 = xr[384];
  }
  __syncthreads();
  for (int s = 0; s < SS; ++s) {
    const int sf = dir ? (SS-1-s) : s;
    const float* hs = hl + ks*64;
    float a0 = 0.f, a1 = 0.f, a2 = 0.f, a3 = 0.f;
    #pragma unroll
    for (int j = 0; j < 16; j += 4) {
      float4 h0 = *(const float4*)(hs + j*4);
      float4 h1 = *(const float4*)(hs + j*4 + 4);
      float4 h2 = *(const float4*)(hs + j*4 + 8);
      float4 h3 = *(const float4*)(hs + j*4 + 12);
      a0 += wr[j].x*h0.x + wr[j].y*h0.y + wr[j].z*h0.z + wr[j].w*h0.w;
      a1 += wr[j+1].x*h1.x + wr[j+1].y*h1.y + wr[j+1].z*h1.z + wr[j+1].w*h1.w;
      a2 += wr[j+2].x*h2.x + wr[j+2].y*h2.y + wr[j+2].z*h2.z + wr[j+2].w*h2.w;
      a3 += wr[j+3].x*h3.x + wr[j+3].y*h3.y + wr[j+3].z*h3.z + wr[j+3].w*h3.w;
    }
    part[ks][row] = (a0 + a1) + (a2 + a3);
    float nx0 = 0.f, nx1 = 0.f, nx2 = 0.f, nx3 = 0.f;
    if (t < 128 && s + 1 < SS) {
      const int sfn = dir ? (SS-2-s) : (s+1);
      const float* xr = xcomb + (sfn*NB + b)*1024 + dir*512 + t;
      nx0 = xr[0]; nx1 = xr[128]; nx2 = xr[256]; nx3 = xr[384];
    }
    LBAR();
    if (t < 128) {
      float gi = part[0][t]       + part[1][t]       + xv0;
      float gf = part[0][128 + t] + part[1][128 + t] + xv1;
      float gg = part[0][256 + t] + part[1][256 + t] + xv2;
      float go = part[0][384 + t] + part[1][384 + t] + xv3;
      float iv = sigmf(gi), fv = sigmf(gf), gv = tanhf_(gg), ov = sigmf(go);
      c_reg = fv*c_reg + iv*gv;
      float hv = ov*tanhf_(c_reg);
      hl[t] = hv;
      encout[(b*SS + sf)*HH + dir*HL + t] = hv;
    }
    LBAR();
    xv0 = nx0; xv1 = nx1; xv2 = nx2; xv3 = nx3;
  }
  if (t < 128) {
    hpub[b*HH + dir*HL + t] = hl[t];
    c0buf[b*HH + dir*HL + t] = c_reg;
  }
}

// ---------- fused: enc_ws (blocks 0..199) + encproj = Wc@enc_out in bf16 (blocks 200..599) ----------
__global__ __launch_bounds__(256) void k_encws_proj(
    const float* __restrict__ encout,
    const float* __restrict__ asW, const float* __restrict__ asb,
    float* __restrict__ encwsR,
    const short* __restrict__ dwCb,
    short* __restrict__ encprojB)
{
  const int tid = threadIdx.x;
  if (blockIdx.x < 200) {
    const int rt = blockIdx.x;
    __shared__ float Al[32*260];
    #pragma unroll
    for (int i = 0; i < 32; ++i) {
      int l = tid + i*256;
      int r = l >> 8, k = l & 255;
      Al[r*260 + k] = encout[(rt*32 + r)*256 + k];
    }
    __syncthreads();
    const int a = tid & 63, rg = tid >> 6;
    float acc[8];
    #pragma unroll
    for (int q = 0; q < 8; ++q) acc[q] = 0.0f;
    const float4* w4 = (const float4*)(asW + a*256);
    for (int k4 = 0; k4 < 64; ++k4) {
      float4 w = w4[k4];
      #pragma unroll
      for (int q = 0; q < 8; ++q) {
        const float4* a4 = (const float4*)(Al + (rg*8 + q)*260);
        float4 av = a4[k4];
        acc[q] += av.x*w.x + av.y*w.y + av.z*w.z + av.w*w.w;
      }
    }
    float bias = asb[a];
    #pragma unroll
    for (int q = 0; q < 8; ++q) {
      int row = rt*32 + rg*8 + q;
      encwsR[row*64 + a] = acc[q] + bias;
    }
  } else {
    const int bid = blockIdx.x - 200;   // 0..399
    const int m0 = (bid >> 2) * 64;     // 100 row tiles
    const int c0 = (bid & 3) * 256;     // 4 col chunks
    const int t = tid;
    const int w = t >> 6, l = t & 63;
    __shared__ short Abuf[64*264];
    {
      const int ar = t >> 2, ak0 = (t & 3) * 64;
      const float* src = encout + (size_t)(m0 + ar)*256 + ak0;
      #pragma unroll
      for (int j = 0; j < 16; ++j) {
        float4 v = *(const float4*)(src + 4*j);
        short4 s4; s4.x = f2bf(v.x); s4.y = f2bf(v.y); s4.z = f2bf(v.z); s4.w = f2bf(v.w);
        *(short4*)(&Abuf[ar*264 + ak0 + 4*j]) = s4;
      }
    }
    LBAR();
    f32x4 acc[4][4];
    #pragma unroll
    for (int i = 0; i < 4; ++i)
      #pragma unroll
      for (int j = 0; j < 4; ++j) acc[i][j] = (f32x4){0.f,0.f,0.f,0.f};
    #pragma unroll
    for (int kst = 0; kst < 8; ++kst) {
      bf16x8 af[4];
      #pragma unroll
      for (int mr = 0; mr < 4; ++mr)
        af[mr] = *(const bf16x8*)(&Abuf[(mr*16 + (l & 15))*264 + kst*32 + (l >> 4)*8]);
      #pragma unroll
      for (int ct = 0; ct < 4; ++ct) {
        int col = c0 + w*64 + ct*16 + (l & 15);
        bf16x8 bfr = *(const bf16x8*)(dwCb + (size_t)col*256 + kst*32 + (l >> 4)*8);
        #pragma unroll
        for (int mr = 0; mr < 4; ++mr)
          acc[mr][ct] = __builtin_amdgcn_mfma_f32_16x16x32_bf16(af[mr], bfr, acc[mr][ct], 0, 0, 0);
      }
    }
    #pragma unroll
    for (int ct = 0; ct < 4; ++ct) {
      int col = c0 + w*64 + ct*16 + (l & 15);
      #pragma unroll
      for (int mr = 0; mr < 4; ++mr) {
        #pragma unroll
        for (int r = 0; r < 4; ++r) {
          int R = m0 + mr*16 + (l >> 4)*4 + r;
          encprojB[(size_t)R*1024 + col] = f2bf(acc[mr][ct][r]);
        }
      }
    }
  }
}

// ---------- decoder: 8 WGs x 16 batches; ONE exchange/step; ctx via encproj linearity ----------
__global__ __launch_bounds__(1024, 4) void k_decoder(
    const float* __restrict__ decpre,
    const float* __restrict__ dwhh,   // [1024][256]
    const float* __restrict__ ahW, const float* __restrict__ ahb,
    const float* __restrict__ afW, const float* __restrict__ afb,
    const float* __restrict__ encwsR, // [b*400+s][64]
    const short* __restrict__ encprojB, // [b*400+s][1024] bf16
    const int* __restrict__ alen,
    const float* __restrict__ c0buf,
    float* hpub, float* wpub,
    float* __restrict__ dhall,
    int* flags)
{
  const int wg = blockIdx.x;
  const int g = wg >> 4, b = wg & 15;
  const int t = threadIdx.x;
  const int r = t & 127, ks = t >> 7;   // row (128), slice (8)
  const int lane = t & 63;
  const int u = t & 31;
  const int grow = (r >> 5)*256 + g*32 + (r & 31);

  // Whh slice: 32 floats (K = ks*32 .. +32)
  float4 wr[8];
  #pragma unroll
  for (int j = 0; j < 8; ++j) {
    wr[j] = *(const float4*)(dwhh + grow*256 + ks*32 + j*4);
    PIN4(wr[j]);
  }

  __shared__ float wsl[400*68 + 16];   // enc_ws full for batch b (~109KB)
  __shared__ float ahWt[32*68];        // this WG's 32 unit rows of ahW^T
  __shared__ float hsh[256];
  __shared__ float part[8][132];       // Whh partials
  __shared__ float part2[8][132];      // ctx-gate partials (from prev step's X)
  __shared__ float wh[64];
  __shared__ float fwl[64];
  __shared__ float scl[448];
  __shared__ float red[16];

  for (int i = t; i < 400*64; i += 1024) {
    int si = i >> 6, a = i & 63;
    wsl[si*68 + a] = encwsR[(b*SS + si)*64 + a];
  }
  for (int i = t; i < 32*64; i += 1024) {
    int u2 = i >> 6, a = i & 63;
    ahWt[u2*68 + a] = ahW[a*HH + g*32 + u2];
  }
  for (int i = t; i < 8*132; i += 1024) ((float*)part2)[i] = 0.0f;
  if (t < 64) fwl[t] = afW[t];
  const float fb0 = afb[0];
  int len = alen[b]; len = min(max(len, 1), SS);
  float c_reg = 0.f;
  float pre0 = 0.f, pre1 = 0.f, pre2 = 0.f, pre3 = 0.f;
  if (t < 256) {
    c_reg = c0buf[b*HH + g*32 + u];
    hsh[t] = gload(hpub + b*HH + t);
    const float* pr = decpre + (size_t)(0*NB + b)*1024 + g*32 + u;
    pre0 = pr[0]; pre1 = pr[256]; pre2 = pr[512]; pre3 = pr[768];
  }
  __syncthreads();

  for (int tt = 0; tt < TT; ++tt) {
    // ---- phase G: Whh @ h (32 MACs/thread) ----
    {
      const float* hs = hsh + ks*32;
      float a0 = 0.f, a1 = 0.f;
      #pragma unroll
      for (int j = 0; j < 8; j += 2) {
        float4 h0 = *(const float4*)(hs + j*4);
        float4 h1 = *(const float4*)(hs + j*4 + 4);
        a0 += wr[j].x*h0.x + wr[j].y*h0.y + wr[j].z*h0.z + wr[j].w*h0.w;
        a1 += wr[j+1].x*h1.x + wr[j+1].y*h1.y + wr[j+1].z*h1.z + wr[j+1].w*h1.w;
      }
      part[ks][r] = a0 + a1;
    }
    LBAR();
    // ---- phase C: reduce (Whh + ctx partials) + cell + whpart ----
    if (t < 256) {
      float g0 = pre0, g1 = pre1, g2 = pre2, g3 = pre3;
      #pragma unroll
      for (int j = 0; j < 8; ++j) {
        g0 += part[j][u]      + part2[j][u];
        g1 += part[j][32 + u] + part2[j][32 + u];
        g2 += part[j][64 + u] + part2[j][64 + u];
        g3 += part[j][96 + u] + part2[j][96 + u];
      }
      float iv = sigmf(g0), fv = sigmf(g1), gv = tanhf_(g2), ov = sigmf(g3);
      c_reg = fv*c_reg + iv*gv;
      float hv = ov*tanhf_(c_reg);
      if (t < 32) {
        gstore(hpub + b*HH + g*32 + t, hv);
        dhall[(tt*NB + b)*HH + g*32 + t] = hv;
      }
      int wv = t >> 6;
      int a = wv*16 + (lane >> 2);
      int j4 = lane & 3;
      float wacc = 0.f;
      #pragma unroll
      for (int i = 0; i < 8; ++i) {
        int u2 = j4*8 + i;
        float hx = __shfl(hv, u2, 64);
        wacc += ahWt[u2*68 + a] * hx;
      }
      wacc += __shfl_xor(wacc, 1);
      wacc += __shfl_xor(wacc, 2);
      if (j4 == 0) gstore(wpub + (b*8 + g)*72 + a, wacc);
    }
    flagbar(flags, b, g, tt + 1);
    if (tt == TT - 1) break;
    // ---- phase SW: stage h + prefetch decpre; wh combine on wave 4 ----
    if (t < 256) {
      hsh[t] = gload(hpub + b*HH + t);
      const float* pr = decpre + (size_t)((tt+1)*NB + b)*1024 + g*32 + u;
      pre0 = pr[0]; pre1 = pr[256]; pre2 = pr[512]; pre3 = pr[768];
    } else if (t < 320) {
      int a = t - 256;
      float s = ahb[a];
      #pragma unroll
      for (int j = 0; j < 8; ++j) s += gload(wpub + (b*8 + j)*72 + a);
      wh[a] = s;
    }
    LBAR();
    // ---- phase F: ALL 400 scores (2 threads/s, 32 terms each) ----
    if (t < 800) {
      int s = t >> 1, half = t & 1;
      const float* wrow = wsl + s*68 + half*32;
      const float* whh = wh + half*32;
      const float* fw = fwl + half*32;
      float p = 0.f;
      #pragma unroll
      for (int j = 0; j < 32; ++j) p += fw[j] * tanhf_(wrow[j] + whh[j]);
      p += __shfl_xor(p, 1);
      if (half == 0) {
        float sc = fb0 + p;
        sc = fminf(sc, (s < len) ? 9999.0f : -9999.0f);
        scl[s] = sc;
      }
    }
    LBAR();
    // ---- phase M1: per-wave max (waves 0..6) ----
    {
      float v = (t < 400) ? scl[t] : -1e30f;
      float m = v;
      #pragma unroll
      for (int o = 32; o; o >>= 1) m = fmaxf(m, __shfl_xor(m, o));
      if (t < 448 && lane == 0) red[t >> 6] = m;
    }
    LBAR();
    // ---- phase M2: exp + per-wave sum ----
    {
      float M = red[0];
      #pragma unroll
      for (int i = 1; i < 7; ++i) M = fmaxf(M, red[i]);
      float p = (t < 400) ? __expf(scl[t] - M) : 0.0f;
      if (t < 400) scl[t] = p;
      float ssum = p;
      #pragma unroll
      for (int o = 32; o; o >>= 1) ssum += __shfl_xor(ssum, o);
      if (t < 448 && lane == 0) red[8 + (t >> 6)] = ssum;
    }
    LBAR();
    // ---- phase X: ctx-gate partials for NEXT step (50 L2 loads/thread) ----
    {
      float ssum = red[8];
      #pragma unroll
      for (int i = 9; i < 15; ++i) ssum += red[i];
      float inv = 1.0f / ssum;
      const unsigned short* ep = (const unsigned short*)(encprojB) +
                                 (size_t)(b*SS + ks*50)*1024 + grow;
      float acc = 0.f;
      #pragma unroll 10
      for (int i = 0; i < 50; ++i)
        acc += scl[ks*50 + i] * bf2f(ep[(size_t)i*1024]);
      part2[ks][r] = acc * inv;
    }
    LBAR();
  }
}

// ---------- vocab logits via MFMA + per-chunk logsumexp partials ----------
__global__ __launch_bounds__(256) void k_pred_mfma(
    const float* __restrict__ dhall,
    const short* __restrict__ predWb,
    const float* __restrict__ predb,
    float* __restrict__ pm, float* __restrict__ ps)
{
  const int m0 = blockIdx.x * 64;
  const int ch = blockIdx.y;
  const int c0 = ch * 256;
  const int t = threadIdx.x;
  const int w = t >> 6, l = t & 63;
  __shared__ __align__(16) char smem[64*264*4];
  short* Abuf = (short*)smem;
  float* L    = (float*)smem;
  __shared__ float red[256];
  __shared__ float rowmax[64];

  {
    const int ar = t >> 2, ak0 = (t & 3) * 64;
    const float* src = dhall + (size_t)(m0 + ar)*256 + ak0;
    #pragma unroll
    for (int j = 0; j < 16; ++j) {
      float4 v = *(const float4*)(src + 4*j);
      short4 s4; s4.x = f2bf(v.x); s4.y = f2bf(v.y); s4.z = f2bf(v.z); s4.w = f2bf(v.w);
      *(short4*)(&Abuf[ar*264 + ak0 + 4*j]) = s4;
    }
  }
  LBAR();
  f32x4 acc[4][4];
  #pragma unroll
  for (int i = 0; i < 4; ++i)
    #pragma unroll
    for (int j = 0; j < 4; ++j) acc[i][j] = (f32x4){0.f,0.f,0.f,0.f};
  #pragma unroll
  for (int kst = 0; kst < 8; ++kst) {
    bf16x8 af[4];
    #pragma unroll
    for (int mr = 0; mr < 4; ++mr)
      af[mr] = *(const bf16x8*)(&Abuf[(mr*16 + (l & 15))*264 + kst*32 + (l >> 4)*8]);
    #pragma unroll
    for (int ct = 0; ct < 4; ++ct) {
      int col = c0 + w*64 + ct*16 + (l & 15);
      bf16x8 bfr = *(const bf16x8*)(predWb + (size_t)col*256 + kst*32 + (l >> 4)*8);
      #pragma unroll
      for (int mr = 0; mr < 4; ++mr)
        acc[mr][ct] = __builtin_amdgcn_mfma_f32_16x16x32_bf16(af[mr], bfr, acc[mr][ct], 0, 0, 0);
    }
  }
  LBAR();
  #pragma unroll
  for (int ct = 0; ct < 4; ++ct) {
    int col = c0 + w*64 + ct*16 + (l & 15);
    float bias = (col < VV) ? predb[col] : 0.0f;
    bool valid = (col < VV);
    #pragma unroll
    for (int mr = 0; mr < 4; ++mr) {
      #pragma unroll
      for (int r = 0; r < 4; ++r) {
        int rl = mr*16 + (l >> 4)*4 + r;
        L[rl*264 + w*64 + ct*16 + (l & 15)] = valid ? (acc[mr][ct][r] + bias) : -1e30f;
      }
    }
  }
  LBAR();
  {
    const int row = t & 63, qd = t >> 6;
    float m = -1e30f;
    const float* Lr = L + row*264 + qd*64;
    for (int i = 0; i < 64; ++i) m = fmaxf(m, Lr[i]);
    red[qd*64 + row] = m;
  }
  LBAR();
  if (t < 64) {
    float m = fmaxf(fmaxf(red[t], red[64+t]), fmaxf(red[128+t], red[192+t]));
    rowmax[t] = m;
  }
  LBAR();
  {
    const int row = t & 63, qd = t >> 6;
    float m = rowmax[row];
    float ssum = 0.f;
    const float* Lr = L + row*264 + qd*64;
    for (int i = 0; i < 64; ++i) ssum += __expf(Lr[i] - m);
    red[qd*64 + row] = ssum;
  }
  LBAR();
  if (t < 64) {
    float ssum = red[t] + red[64+t] + red[128+t] + red[192+t];
    pm[(m0 + t)*NCHUNK + ch] = rowmax[t];
    ps[(m0 + t)*NCHUNK + ch] = ssum;
  }
}

// ---------- loss partials ----------
__global__ __launch_bounds__(256) void k_loss_part(
    const float* __restrict__ pm, const float* __restrict__ ps,
    const float* __restrict__ dhall,
    const float* __restrict__ predW, const float* __restrict__ predb,
    const int* __restrict__ abstr, float* __restrict__ lpart)
{
  const int tid = threadIdx.x;
  const int row = blockIdx.x*256 + tid;
  __shared__ float rs[256], rc[256];
  float lsum = 0.0f, lcnt = 0.0f;
  {
    int t = row >> 4, b = row & 15;
    int tok = abstr[b*TT + t];
    float m = -1e30f;
    for (int c = 0; c < NCHUNK; ++c) m = fmaxf(m, pm[row*NCHUNK + c]);
    float ss = 0.0f;
    for (int c = 0; c < NCHUNK; ++c) ss += ps[row*NCHUNK + c] * __expf(pm[row*NCHUNK + c] - m);
    float lse = m + __logf(ss);
    float tl = predb[tok];
    const float* hrow = dhall + row*256;
    const float* wrow = predW + tok*256;
    #pragma unroll 4
    for (int k = 0; k < 256; ++k) tl += hrow[k] * wrow[k];
    if (tok != 0) { lsum = lse - tl; lcnt = 1.0f; }
  }
  rs[tid] = lsum; rc[tid] = lcnt;
  __syncthreads();
  for (int st = 128; st; st >>= 1) {
    if (tid < st) { rs[tid] += rs[tid + st]; rc[tid] += rc[tid + st]; }
    __syncthreads();
  }
  if (tid == 0) { lpart[blockIdx.x*2] = rs[0]; lpart[blockIdx.x*2 + 1] = rc[0]; }
}

// ---------- final ----------
__global__ void k_loss_final(const float* __restrict__ lpart, float* __restrict__ out) {
  if (threadIdx.x == 0) {
    float s = 0.f, c = 0.f;
    for (int i = 0; i < 6; ++i) { s += lpart[i*2]; c += lpart[i*2 + 1]; }
    out[0] = s / fmaxf(c, 1.0f);
  }
}

// ---------- launch ----------
extern "C" void kernel_launch(void* const* d_in, const int* in_sizes, int n_in,
                              void* d_out, int out_size, void* d_ws, size_t ws_size,
                              hipStream_t stream) {
  const float* emb   = (const float*)d_in[0];
  const int* article = (const int*)d_in[1];
  const int* alen    = (const int*)d_in[2];
  const int* abstr   = (const int*)d_in[3];
  const float* eWihF = (const float*)d_in[4];
  const float* eWhhF = (const float*)d_in[5];
  const float* ebF   = (const float*)d_in[6];
  const float* eWihB = (const float*)d_in[7];
  const float* eWhhB = (const float*)d_in[8];
  const float* ebB   = (const float*)d_in[9];
  const float* dWih  = (const float*)d_in[10];
  const float* dWhh  = (const float*)d_in[11];
  const float* db    = (const float*)d_in[12];
  const float* pW    = (const float*)d_in[13];
  const float* pb    = (const float*)d_in[14];
  const float* asW   = (const float*)d_in[15];
  const float* asb   = (const float*)d_in[16];
  const float* ahW   = (const float*)d_in[17];
  const float* ahb   = (const float*)d_in[18];
  const float* afW   = (const float*)d_in[19];
  const float* afb   = (const float*)d_in[20];
  float* out = (float*)d_out;

  float* w = (float*)d_ws;
  size_t o = 0;
  float* xcomb  = w + o; o += (size_t)SS*NB*1024;   // reused as encprojB after encoder
  float* encout = w + o; o += (size_t)NB*SS*HH;
  float* encwsR = w + o; o += (size_t)NB*SS*AA;
  float* decpre = w + o; o += (size_t)TT*NB*1024;
  float* dhall  = w + o; o += (size_t)TT*NB*HH;
  float* hpub   = w + o; o += NB*HH;
  float* wpub   = w + o; o += NB*8*72;
  float* c0buf  = w + o; o += NB*HH;
  float* pm     = w + o; o += (size_t)TT*NB*NCHUNK;
  float* ps     = w + o; o += (size_t)TT*NB*NCHUNK;
  float* lpart  = w + o; o += 16;
  int* flags = (int*)(w + o); o += 128;
  short* predWb = (short*)(w + o); o += (size_t)VVP*256/2;
  short* wfB    = (short*)(w + o); o += 512*1024/2;
  short* wbB    = (short*)(w + o); o += 512*1024/2;
  short* dwB    = (short*)(w + o); o += 1024*1024/2;
  short* dwCb   = (short*)(w + o); o += 1024*256/2;
  short* encprojB = (short*)xcomb;   // alias: xcomb dead after k_encoder

  k_init<<<1, 256, 0, stream>>>(flags);
  k_casts<<<512, 256, 0, stream>>>(eWihF, eWihB, dWih, wfB, wbB, dwB, dwCb);
  k_embproj_enc_mfma<<<dim3(100, 4), 256, 0, stream>>>(emb, article, wfB, wbB, ebF, ebB, xcomb);
  k_embproj_dec_mfma<<<dim3(24, 4), 256, 0, stream>>>(emb, abstr, dwB, db, decpre);
  k_encoder<<<256, 1024, 0, stream>>>(xcomb, eWhhF, eWhhB, encout, hpub, c0buf, pW, predWb);
  k_encws_proj<<<600, 256, 0, stream>>>(encout, asW, asb, encwsR, dwCb, encprojB);
  k_decoder<<<128, 1024, 0, stream>>>(decpre, dWhh, ahW, ahb, afW, afb,
                                      encwsR, encprojB, alen, c0buf, hpub, wpub, dhall, flags);
  k_pred_mfma<<<dim3(24, 120), 256, 0, stream>>>(dhall, predWb, pb, pm, ps);
  k_loss_part<<<6, 256, 0, stream>>>(pm, ps, dhall, pW, pb, abstr, lpart);
  k_loss_final<<<1, 64, 0, stream>>>(lpart, out);
}

// Round 14
// 1599.852 us; speedup vs baseline: 1.0343x; 1.0343x over previous
//
#include <hip/hip_runtime.h>
#include <cmath>

#define NB 16      // batch
#define SS 400     // source len
#define TT 96      // target len
#define HL 128     // LSTM per dir
#define HH 256     // decoder hidden (2*HL)
#define AA 64      // attn dim
#define VV 30611   // vocab
#define VVP 30720  // vocab padded to 256
#define START_TOK 101
#define NCHUNK 120 // vocab chunks of 256

typedef __attribute__((ext_vector_type(8))) short bf16x8;
typedef __attribute__((ext_vector_type(4))) float f32x4;

// keep a loaded float4 live in VGPRs (forbid rematerialization / load sinking)
#define PIN4(v) asm volatile("" : "+v"((v).x), "+v"((v).y), "+v"((v).z), "+v"((v).w))
// LDS-only barrier: no vmcnt drain (global stores stay in flight)
#define LBAR() asm volatile("s_waitcnt lgkmcnt(0)\n\ts_barrier" ::: "memory")

// ---------- helpers ----------
__device__ __forceinline__ float gload(const float* p) {
  return __hip_atomic_load(p, __ATOMIC_RELAXED, __HIP_MEMORY_SCOPE_AGENT);
}
__device__ __forceinline__ void gstore(float* p, float v) {
  __hip_atomic_store(p, v, __ATOMIC_RELAXED, __HIP_MEMORY_SCOPE_AGENT);
}
__device__ __forceinline__ float sigmf(float x) { return 1.0f / (1.0f + __expf(-x)); }
__device__ __forceinline__ float tanhf_(float x) {
  float xc = fminf(fmaxf(x, -15.0f), 15.0f);
  return 1.0f - 2.0f / (__expf(2.0f * xc) + 1.0f);
}
__device__ __forceinline__ short f2bf(float f) {
  unsigned u = __float_as_uint(f);
  unsigned r = (u + 0x7FFFu + ((u >> 16) & 1u)) >> 16;
  return (short)r;
}
// flag barrier, RELAXED-only protocol (round 8, verified): all cross-WG data
// moves via relaxed agent-scope atomics (LLC-coherent, bypass L2), so no
// acquire/release cache maintenance is needed. __syncthreads drains each
// wave's vmcnt (data acked at LLC), then flag store, poll, LBAR broadcast.
__device__ __forceinline__ void flagbar(int* flags, int b, int g, int target) {
  __syncthreads();
  if (threadIdx.x == 0)
    __hip_atomic_store(&flags[b*8 + g], target, __ATOMIC_RELAXED, __HIP_MEMORY_SCOPE_AGENT);
  if (threadIdx.x < 8) {
    while (__hip_atomic_load(&flags[b*8 + threadIdx.x], __ATOMIC_RELAXED, __HIP_MEMORY_SCOPE_AGENT) < target)
      __builtin_amdgcn_s_sleep(1);
  }
  LBAR();
}

// ---------- init: zero flags ----------
__global__ __launch_bounds__(256) void k_init(int* flags) {
  if (threadIdx.x < 128) flags[threadIdx.x] = 0;
}

// ---------- cast LSTM weights to bf16 (predW cast fused into k_encoder) ----------
__global__ __launch_bounds__(256) void k_casts(
    const float* __restrict__ wf, const float* __restrict__ wb,
    const float* __restrict__ dwih,
    short* __restrict__ wfB, short* __restrict__ wbB, short* __restrict__ dwB)
{
  const int stride = gridDim.x * 256;
  const int t0 = blockIdx.x * 256 + threadIdx.x;
  for (int i = t0; i < 512*1024; i += stride) wfB[i] = f2bf(wf[i]);
  for (int i = t0; i < 512*1024; i += stride) wbB[i] = f2bf(wb[i]);
  for (int i = t0; i < 1024*1024; i += stride) {
    int r = i >> 10, k = i & 1023;
    dwB[i] = f2bf(dwih[r*1280 + k]);
  }
}

// ---------- encoder input projection via MFMA ----------
__global__ __launch_bounds__(256) void k_embproj_enc_mfma(
    const float* __restrict__ emb, const int* __restrict__ article,
    const short* __restrict__ wfB, const short* __restrict__ wbB,
    const float* __restrict__ bf, const float* __restrict__ bb,
    float* __restrict__ xcomb)
{
  const int m0 = blockIdx.x * 64;
  const int n0 = blockIdx.y * 256;
  const int t = threadIdx.x;
  const int w = t >> 6, l = t & 63;
  __shared__ short Abuf[64*136];
  __shared__ int tok[64];
  if (t < 64) {
    int R = m0 + t, s = R >> 4, b = R & 15;
    tok[t] = article[b*SS + s];
  }
  const short* __restrict__ Wb = (n0 < 512) ? wfB : wbB;
  const int nb0 = (n0 < 512) ? n0 : (n0 - 512);
  f32x4 acc[4][4];
  #pragma unroll
  for (int i = 0; i < 4; ++i)
    #pragma unroll
    for (int j = 0; j < 4; ++j) acc[i][j] = (f32x4){0.f,0.f,0.f,0.f};
  __syncthreads();
  const int ar = t >> 2, ak0 = (t & 3) * 32;
  for (int kc = 0; kc < 8; ++kc) {
    const float* src = emb + (size_t)tok[ar]*1024 + kc*128 + ak0;
    #pragma unroll
    for (int j = 0; j < 8; ++j) {
      float4 v = *(const float4*)(src + 4*j);
      short4 s4; s4.x = f2bf(v.x); s4.y = f2bf(v.y); s4.z = f2bf(v.z); s4.w = f2bf(v.w);
      *(short4*)(&Abuf[ar*136 + ak0 + 4*j]) = s4;
    }
    LBAR();
    #pragma unroll
    for (int ks = 0; ks < 4; ++ks) {
      bf16x8 af[4];
      #pragma unroll
      for (int mr = 0; mr < 4; ++mr)
        af[mr] = *(const bf16x8*)(&Abuf[(mr*16 + (l & 15))*136 + ks*32 + (l >> 4)*8]);
      #pragma unroll
      for (int ct = 0; ct < 4; ++ct) {
        int n = nb0 + w*64 + ct*16 + (l & 15);
        bf16x8 bfr = *(const bf16x8*)(Wb + (size_t)n*1024 + kc*128 + ks*32 + (l >> 4)*8);
        #pragma unroll
        for (int mr = 0; mr < 4; ++mr)
          acc[mr][ct] = __builtin_amdgcn_mfma_f32_16x16x32_bf16(af[mr], bfr, acc[mr][ct], 0, 0, 0);
      }
    }
    LBAR();
  }
  #pragma unroll
  for (int ct = 0; ct < 4; ++ct) {
    int n = n0 + w*64 + ct*16 + (l & 15);
    float bias = (n < 512) ? bf[n] : bb[n - 512];
    #pragma unroll
    for (int mr = 0; mr < 4; ++mr) {
      #pragma unroll
      for (int r = 0; r < 4; ++r) {
        int R = m0 + mr*16 + (l >> 4)*4 + r;
        xcomb[(size_t)R*1024 + n] = acc[mr][ct][r] + bias;
      }
    }
  }
}

// ---------- fused launch: encoder recurrence (blocks 0..31) +
//            decoder embedding projection (blocks 32..55, 1024 thr, 4 col chunks) +
//            predW bf16 cast (blocks 56..255) ----------
__global__ __launch_bounds__(1024, 4) void k_encoder(
    const float* __restrict__ xcomb,
    const float* __restrict__ whhf, const float* __restrict__ whhb,
    float* __restrict__ encout,
    float* __restrict__ hpub,
    float* __restrict__ c0buf,
    const float* __restrict__ predW, short* __restrict__ predWb,
    const float* __restrict__ emb, const int* __restrict__ abstr,
    const short* __restrict__ dwB, const float* __restrict__ db,
    float* __restrict__ decpre)
{
  const int t = threadIdx.x;
  __shared__ float hl[128];
  __shared__ float part[2][512];
  __shared__ short Abuf[64*136];
  __shared__ int tok[64];

  if (blockIdx.x >= 56) {
    // ---- fused predW cast on otherwise-idle CUs ----
    const size_t idx0 = (size_t)(blockIdx.x - 56) * 1024 + t;
    const size_t stride = (size_t)200 * 1024;
    for (size_t i = idx0; i < (size_t)VVP*256; i += stride)
      predWb[i] = (i < (size_t)VV*256) ? f2bf(predW[i]) : (short)0;
    return;
  }
  if (blockIdx.x >= 32) {
    // ---- fused decoder embedding projection: decpre = emb[tok] @ dwB^T + db ----
    const int m0 = (blockIdx.x - 32) * 64;   // 24 row tiles of 64
    const int sub = t & 255, w2 = t >> 8;    // 4 col chunks of 256
    const int w = sub >> 6, l = sub & 63;
    if (t < 64) {
      int R = m0 + t, tt2 = R >> 4, bb = R & 15;
      tok[t] = (tt2 == 0) ? START_TOK : abstr[bb*TT + tt2 - 1];
    }
    f32x4 acc[4][4];
    #pragma unroll
    for (int i = 0; i < 4; ++i)
      #pragma unroll
      for (int j = 0; j < 4; ++j) acc[i][j] = (f32x4){0.f,0.f,0.f,0.f};
    __syncthreads();
    const int ar = sub >> 2, ak0 = (sub & 3) * 32;
    for (int kc = 0; kc < 8; ++kc) {
      if (w2 == 0) {
        const float* src = emb + (size_t)tok[ar]*1024 + kc*128 + ak0;
        #pragma unroll
        for (int j = 0; j < 8; ++j) {
          float4 v = *(const float4*)(src + 4*j);
          short4 s4; s4.x = f2bf(v.x); s4.y = f2bf(v.y); s4.z = f2bf(v.z); s4.w = f2bf(v.w);
          *(short4*)(&Abuf[ar*136 + ak0 + 4*j]) = s4;
        }
      }
      LBAR();
      #pragma unroll
      for (int ks = 0; ks < 4; ++ks) {
        bf16x8 af[4];
        #pragma unroll
        for (int mr = 0; mr < 4; ++mr)
          af[mr] = *(const bf16x8*)(&Abuf[(mr*16 + (l & 15))*136 + ks*32 + (l >> 4)*8]);
        #pragma unroll
        for (int ct = 0; ct < 4; ++ct) {
          int n = w2*256 + w*64 + ct*16 + (l & 15);
          bf16x8 bfr = *(const bf16x8*)(dwB + (size_t)n*1024 + kc*128 + ks*32 + (l >> 4)*8);
          #pragma unroll
          for (int mr = 0; mr < 4; ++mr)
            acc[mr][ct] = __builtin_amdgcn_mfma_f32_16x16x32_bf16(af[mr], bfr, acc[mr][ct], 0, 0, 0);
        }
      }
      LBAR();
    }
    #pragma unroll
    for (int ct = 0; ct < 4; ++ct) {
      int n = w2*256 + w*64 + ct*16 + (l & 15);
      float bias = db[n];
      #pragma unroll
      for (int mr = 0; mr < 4; ++mr) {
        #pragma unroll
        for (int r = 0; r < 4; ++r) {
          int R = m0 + mr*16 + (l >> 4)*4 + r;
          decpre[(size_t)R*1024 + n] = acc[mr][ct][r] + bias;
        }
      }
    }
    return;
  }
  // ---- encoder recurrence (blocks 0..31) ----
  const int b = blockIdx.x & 15, dir = blockIdx.x >> 4;
  const int row = t & 511;
  const int ks = t >> 9;
  const float* __restrict__ Whh = dir ? whhb : whhf;
  float4 wr[16];
  #pragma unroll
  for (int j = 0; j < 16; ++j) {
    wr[j] = *(const float4*)(Whh + row*128 + ks*64 + j*4);
    PIN4(wr[j]);
  }
  float c_reg = 0.0f;
  if (t < 128) hl[t] = 0.0f;
  float xv0 = 0.f, xv1 = 0.f, xv2 = 0.f, xv3 = 0.f;
  if (t < 128) {
    const float* xr = xcomb + ((dir ? (SS-1) : 0)*NB + b)*1024 + dir*512 + t;
    xv0 = xr[0]; xv1 = xr[128]; xv2 = xr[256]; xv3 = xr[384];
  }
  __syncthreads();
  for (int s = 0; s < SS; ++s) {
    const int sf = dir ? (SS-1-s) : s;
    const float* hs = hl + ks*64;
    float a0 = 0.f, a1 = 0.f, a2 = 0.f, a3 = 0.f;
    #pragma unroll
    for (int j = 0; j < 16; j += 4) {
      float4 h0 = *(const float4*)(hs + j*4);
      float4 h1 = *(const float4*)(hs + j*4 + 4);
      float4 h2 = *(const float4*)(hs + j*4 + 8);
      float4 h3 = *(const float4*)(hs + j*4 + 12);
      a0 += wr[j].x*h0.x + wr[j].y*h0.y + wr[j].z*h0.z + wr[j].w*h0.w;
      a1 += wr[j+1].x*h1.x + wr[j+1].y*h1.y + wr[j+1].z*h1.z + wr[j+1].w*h1.w;
      a2 += wr[j+2].x*h2.x + wr[j+2].y*h2.y + wr[j+2].z*h2.z + wr[j+2].w*h2.w;
      a3 += wr[j+3].x*h3.x + wr[j+3].y*h3.y + wr[j+3].z*h3.z + wr[j+3].w*h3.w;
    }
    part[ks][row] = (a0 + a1) + (a2 + a3);
    float nx0 = 0.f, nx1 = 0.f, nx2 = 0.f, nx3 = 0.f;
    if (t < 128 && s + 1 < SS) {
      const int sfn = dir ? (SS-2-s) : (s+1);
      const float* xr = xcomb + (sfn*NB + b)*1024 + dir*512 + t;
      nx0 = xr[0]; nx1 = xr[128]; nx2 = xr[256]; nx3 = xr[384];
    }
    LBAR();
    if (t < 128) {
      float gi = part[0][t]       + part[1][t]       + xv0;
      float gf = part[0][128 + t] + part[1][128 + t] + xv1;
      float gg = part[0][256 + t] + part[1][256 + t] + xv2;
      float go = part[0][384 + t] + part[1][384 + t] + xv3;
      float iv = sigmf(gi), fv = sigmf(gf), gv = tanhf_(gg), ov = sigmf(go);
      c_reg = fv*c_reg + iv*gv;
      float hv = ov*tanhf_(c_reg);
      hl[t] = hv;
      encout[(b*SS + sf)*HH + dir*HL + t] = hv;
    }
    LBAR();
    xv0 = nx0; xv1 = nx1; xv2 = nx2; xv3 = nx3;
  }
  if (t < 128) {
    hpub[b*HH + dir*HL + t] = hl[t];
    c0buf[b*HH + dir*HL + t] = c_reg;
  }
}

// ---------- enc_ws = enc_out @ attn_s_W.T + b, row-major [b][s][a] ----------
__global__ __launch_bounds__(256) void k_encws(
    const float* __restrict__ encout,
    const float* __restrict__ asW, const float* __restrict__ asb,
    float* __restrict__ encwsR)
{
  const int rt = blockIdx.x;
  const int tid = threadIdx.x;
  __shared__ float Al[32*260];
  #pragma unroll
  for (int i = 0; i < 32; ++i) {
    int l = tid + i*256;
    int r = l >> 8, k = l & 255;
    Al[r*260 + k] = encout[(rt*32 + r)*256 + k];
  }
  __syncthreads();
  const int a = tid & 63, rg = tid >> 6;
  float acc[8];
  #pragma unroll
  for (int q = 0; q < 8; ++q) acc[q] = 0.0f;
  const float4* w4 = (const float4*)(asW + a*256);
  for (int k4 = 0; k4 < 64; ++k4) {
    float4 w = w4[k4];
    #pragma unroll
    for (int q = 0; q < 8; ++q) {
      const float4* a4 = (const float4*)(Al + (rg*8 + q)*260);
      float4 av = a4[k4];
      acc[q] += av.x*w.x + av.y*w.y + av.z*w.z + av.w*w.w;
    }
  }
  float bias = asb[a];
  #pragma unroll
  for (int q = 0; q < 8; ++q) {
    int row = rt*32 + rg*8 + q;
    encwsR[row*64 + a] = acc[q] + bias;
  }
}

// ---------- decoder: 8 WGs x 16 batches; 5 LBARs + 2 relaxed flagbars per step ----------
__global__ __launch_bounds__(1024, 4) void k_decoder(
    const float* __restrict__ decpre,
    const float* __restrict__ dwhh,   // [1024][256]
    const float* __restrict__ dwih,   // [1024][1280]
    const float* __restrict__ ahW, const float* __restrict__ ahb,
    const float* __restrict__ afW, const float* __restrict__ afb,
    const float* __restrict__ encwsR, // [b*400+s][64]
    const float* __restrict__ encout, // [b*400+s][256]
    const int* __restrict__ alen,
    const float* __restrict__ c0buf,  // [16][256]
    float* hpub, float* cpub, float* wpub,
    float* __restrict__ dhall,        // [96*16][256]
    int* flags)
{
  const int wg = blockIdx.x;
  const int g = wg >> 4, b = wg & 15;
  const int t = threadIdx.x;
  const int r = t & 127, ks = t >> 7;
  const int lane = t & 63;
  const int u = t & 31;
  const int s0 = g*50;

  const int grow = (r >> 5)*256 + g*32 + (r & 31);
  float4 wr[16];
  #pragma unroll
  for (int j = 0; j < 16; ++j) {
    int k = ks*64 + j*4;
    wr[j] = (k < 256) ? *(const float4*)(dwhh + grow*256 + k)
                      : *(const float4*)(dwih + grow*1280 + 1024 + (k - 256));
    PIN4(wr[j]);
  }

  __shared__ float encl[50*256];   // 51200 B
  __shared__ float wsl[50*68];     // 13600 B
  __shared__ float ahWt[32*68];    //  8704 B (only this WG's 32 unit rows)
  __shared__ float hc[512];
  __shared__ float part[8][132];
  __shared__ float wh[64];
  __shared__ float fwl[64];
  __shared__ float scl[64];
  __shared__ float sh_m, sh_s;

  for (int i = t; i < 50*256; i += 1024) {
    int si = i >> 8, d = i & 255;
    encl[i] = encout[(b*SS + s0 + si)*HH + d];
  }
  for (int i = t; i < 50*64; i += 1024) {
    int si = i >> 6, a = i & 63;
    wsl[si*68 + a] = encwsR[(b*SS + s0 + si)*64 + a];
  }
  // stage only rows g*32..g*32+32 of ahW^T: ahWt[u2][a] = ahW[a][g*32+u2]
  for (int i = t; i < 32*64; i += 1024) {
    int u2 = i >> 6, a = i & 63;
    ahWt[u2*68 + a] = ahW[a*HH + g*32 + u2];
  }
  if (t < 64) fwl[t] = afW[t];
  const float fb0 = afb[0];
  int len = alen[b]; len = min(max(len, 1), SS);
  float c_reg = 0.f;
  float pre0 = 0.f, pre1 = 0.f, pre2 = 0.f, pre3 = 0.f;
  if (t < 256) {
    c_reg = c0buf[b*HH + g*32 + u];
    hc[t] = gload(hpub + b*HH + t);
    hc[256 + t] = 0.0f;
    const float* pr = decpre + (size_t)(0*NB + b)*1024 + g*32 + u;
    pre0 = pr[0]; pre1 = pr[256]; pre2 = pr[512]; pre3 = pr[768];
  }
  __syncthreads();

  for (int tt = 0; tt < TT; ++tt) {
    // phase G: gates GEMM
    {
      const float* hs = hc + ks*64;
      float a0 = 0.f, a1 = 0.f, a2 = 0.f, a3 = 0.f;
      #pragma unroll
      for (int j = 0; j < 16; j += 4) {
        float4 h0 = *(const float4*)(hs + j*4);
        float4 h1 = *(const float4*)(hs + j*4 + 4);
        float4 h2 = *(const float4*)(hs + j*4 + 8);
        float4 h3 = *(const float4*)(hs + j*4 + 12);
        a0 += wr[j].x*h0.x + wr[j].y*h0.y + wr[j].z*h0.z + wr[j].w*h0.w;
        a1 += wr[j+1].x*h1.x + wr[j+1].y*h1.y + wr[j+1].z*h1.z + wr[j+1].w*h1.w;
        a2 += wr[j+2].x*h2.x + wr[j+2].y*h2.y + wr[j+2].z*h2.z + wr[j+2].w*h2.w;
        a3 += wr[j+3].x*h3.x + wr[j+3].y*h3.y + wr[j+3].z*h3.z + wr[j+3].w*h3.w;
      }
      part[ks][r] = (a0 + a1) + (a2 + a3);
    }
    LBAR();
    // phase C: reduce + cell (t<256, 8x replicated) + whpart via shuffles
    if (t < 256) {
      float g0 = pre0, g1 = pre1, g2 = pre2, g3 = pre3;
      #pragma unroll
      for (int j = 0; j < 8; ++j) {
        g0 += part[j][u];
        g1 += part[j][32 + u];
        g2 += part[j][64 + u];
        g3 += part[j][96 + u];
      }
      float iv = sigmf(g0), fv = sigmf(g1), gv = tanhf_(g2), ov = sigmf(g3);
      c_reg = fv*c_reg + iv*gv;
      float hv = ov*tanhf_(c_reg);
      if (t < 32) {
        gstore(hpub + b*HH + g*32 + t, hv);
        dhall[(tt*NB + b)*HH + g*32 + t] = hv;
      }
      int wv = t >> 6;
      int a = wv*16 + (lane >> 2);
      int j4 = lane & 3;
      float wacc = 0.f;
      #pragma unroll
      for (int i = 0; i < 8; ++i) {
        int u2 = j4*8 + i;
        float hx = __shfl(hv, u2, 64);
        wacc += ahWt[u2*68 + a] * hx;
      }
      wacc += __shfl_xor(wacc, 1);
      wacc += __shfl_xor(wacc, 2);
      if (j4 == 0) gstore(wpub + (b*8 + g)*72 + a, wacc);
    }
    flagbar(flags, b, g, 2*tt + 1);
    // phase SW: stage h + prefetch decpre; wh combine on wave 4
    if (t < 256) {
      hc[t] = gload(hpub + b*HH + t);
      if (tt + 1 < TT) {
        const float* pr = decpre + (size_t)((tt+1)*NB + b)*1024 + g*32 + u;
        pre0 = pr[0]; pre1 = pr[256]; pre2 = pr[512]; pre3 = pr[768];
      }
    } else if (t < 320) {
      int a = t - 256;
      float s = ahb[a];
      #pragma unroll
      for (int j = 0; j < 8; ++j) s += gload(wpub + (b*8 + j)*72 + a);
      wh[a] = s;
    }
    LBAR();
    // phase F: scores
    if (t < 800) {
      int s = t >> 4, j = t & 15;
      const float* wrow = wsl + s*68 + j*4;
      float p = fwl[j*4]   * tanhf_(wrow[0] + wh[j*4])
              + fwl[j*4+1] * tanhf_(wrow[1] + wh[j*4+1])
              + fwl[j*4+2] * tanhf_(wrow[2] + wh[j*4+2])
              + fwl[j*4+3] * tanhf_(wrow[3] + wh[j*4+3]);
      p += __shfl_xor(p, 1);
      p += __shfl_xor(p, 2);
      p += __shfl_xor(p, 4);
      p += __shfl_xor(p, 8);
      if (j == 0) scl[s] = p;
    }
    LBAR();
    // phase M: slice softmax
    if (t < 64) {
      float sc = -1e30f;
      if (t < 50) {
        sc = fb0 + scl[t];
        sc = fminf(sc, (s0 + t < len) ? 9999.0f : -9999.0f);
      }
      float m = sc;
      #pragma unroll
      for (int o = 32; o; o >>= 1) m = fmaxf(m, __shfl_xor(m, o));
      float p = (t < 50) ? __expf(sc - m) : 0.0f;
      scl[t] = p;
      float ssum = p;
      #pragma unroll
      for (int o = 32; o; o >>= 1) ssum += __shfl_xor(ssum, o);
      if (t == 0) { sh_m = m; sh_s = ssum; }
    }
    LBAR();
    // phase X: ctx partial + publish
    if (t < 256) {
      float acc = 0.0f;
      const float* eb = encl + t;
      #pragma unroll 10
      for (int i = 0; i < 50; ++i) acc += scl[i] * eb[i*256];
      gstore(cpub + (b*8 + g)*272 + t, acc);
      if (t == 0) gstore(cpub + (b*8 + g)*272 + 256, sh_m);
      if (t == 1) gstore(cpub + (b*8 + g)*272 + 257, sh_s);
    }
    flagbar(flags, b, g, 2*tt + 2);
    // phase K: combine online-softmax partials
    if (t < 256) {
      float mj[8], sj[8];
      #pragma unroll
      for (int j = 0; j < 8; ++j) {
        mj[j] = gload(cpub + (b*8 + j)*272 + 256);
        sj[j] = gload(cpub + (b*8 + j)*272 + 257);
      }
      float M = mj[0];
      #pragma unroll
      for (int j = 1; j < 8; ++j) M = fmaxf(M, mj[j]);
      float denom = 0.f, ctx = 0.f;
      #pragma unroll
      for (int j = 0; j < 8; ++j) {
        float e = __expf(mj[j] - M);
        denom += sj[j] * e;
        ctx += gload(cpub + (b*8 + j)*272 + t) * e;
      }
      hc[256 + t] = ctx / denom;
    }
    LBAR();
  }
}

// ---------- vocab logits via MFMA + per-chunk logsumexp partials ----------
__global__ __launch_bounds__(256) void k_pred_mfma(
    const float* __restrict__ dhall,
    const short* __restrict__ predWb,
    const float* __restrict__ predb,
    float* __restrict__ pm, float* __restrict__ ps)
{
  const int m0 = blockIdx.x * 64;
  const int ch = blockIdx.y;
  const int c0 = ch * 256;
  const int t = threadIdx.x;
  const int w = t >> 6, l = t & 63;
  __shared__ __align__(16) char smem[64*264*4];
  short* Abuf = (short*)smem;
  float* L    = (float*)smem;
  __shared__ float red[256];
  __shared__ float rowmax[64];

  {
    const int ar = t >> 2, ak0 = (t & 3) * 64;
    const float* src = dhall + (size_t)(m0 + ar)*256 + ak0;
    #pragma unroll
    for (int j = 0; j < 16; ++j) {
      float4 v = *(const float4*)(src + 4*j);
      short4 s4; s4.x = f2bf(v.x); s4.y = f2bf(v.y); s4.z = f2bf(v.z); s4.w = f2bf(v.w);
      *(short4*)(&Abuf[ar*264 + ak0 + 4*j]) = s4;
    }
  }
  LBAR();
  f32x4 acc[4][4];
  #pragma unroll
  for (int i = 0; i < 4; ++i)
    #pragma unroll
    for (int j = 0; j < 4; ++j) acc[i][j] = (f32x4){0.f,0.f,0.f,0.f};
  #pragma unroll
  for (int kst = 0; kst < 8; ++kst) {
    bf16x8 af[4];
    #pragma unroll
    for (int mr = 0; mr < 4; ++mr)
      af[mr] = *(const bf16x8*)(&Abuf[(mr*16 + (l & 15))*264 + kst*32 + (l >> 4)*8]);
    #pragma unroll
    for (int ct = 0; ct < 4; ++ct) {
      int col = c0 + w*64 + ct*16 + (l & 15);
      bf16x8 bfr = *(const bf16x8*)(predWb + (size_t)col*256 + kst*32 + (l >> 4)*8);
      #pragma unroll
      for (int mr = 0; mr < 4; ++mr)
        acc[mr][ct] = __builtin_amdgcn_mfma_f32_16x16x32_bf16(af[mr], bfr, acc[mr][ct], 0, 0, 0);
    }
  }
  LBAR();
  #pragma unroll
  for (int ct = 0; ct < 4; ++ct) {
    int col = c0 + w*64 + ct*16 + (l & 15);
    float bias = (col < VV) ? predb[col] : 0.0f;
    bool valid = (col < VV);
    #pragma unroll
    for (int mr = 0; mr < 4; ++mr) {
      #pragma unroll
      for (int r = 0; r < 4; ++r) {
        int rl = mr*16 + (l >> 4)*4 + r;
        L[rl*264 + w*64 + ct*16 + (l & 15)] = valid ? (acc[mr][ct][r] + bias) : -1e30f;
      }
    }
  }
  LBAR();
  {
    const int row = t & 63, qd = t >> 6;
    float m = -1e30f;
    const float* Lr = L + row*264 + qd*64;
    for (int i = 0; i < 64; ++i) m = fmaxf(m, Lr[i]);
    red[qd*64 + row] = m;
  }
  LBAR();
  if (t < 64) {
    float m = fmaxf(fmaxf(red[t], red[64+t]), fmaxf(red[128+t], red[192+t]));
    rowmax[t] = m;
  }
  LBAR();
  {
    const int row = t & 63, qd = t >> 6;
    float m = rowmax[row];
    float ssum = 0.f;
    const float* Lr = L + row*264 + qd*64;
    for (int i = 0; i < 64; ++i) ssum += __expf(Lr[i] - m);
    red[qd*64 + row] = ssum;
  }
  LBAR();
  if (t < 64) {
    float ssum = red[t] + red[64+t] + red[128+t] + red[192+t];
    pm[(m0 + t)*NCHUNK + ch] = rowmax[t];
    ps[(m0 + t)*NCHUNK + ch] = ssum;
  }
}

// ---------- loss partials: 6 WGs x 256 threads, one row per thread ----------
__global__ __launch_bounds__(256) void k_loss_part(
    const float* __restrict__ pm, const float* __restrict__ ps,
    const float* __restrict__ dhall,
    const float* __restrict__ predW, const float* __restrict__ predb,
    const int* __restrict__ abstr, float* __restrict__ lpart)
{
  const int tid = threadIdx.x;
  const int row = blockIdx.x*256 + tid;
  __shared__ float rs[256], rc[256];
  float lsum = 0.0f, lcnt = 0.0f;
  {
    int t = row >> 4, b = row & 15;
    int tok = abstr[b*TT + t];
    float m = -1e30f;
    for (int c = 0; c < NCHUNK; ++c) m = fmaxf(m, pm[row*NCHUNK + c]);
    float ss = 0.0f;
    for (int c = 0; c < NCHUNK; ++c) ss += ps[row*NCHUNK + c] * __expf(pm[row*NCHUNK + c] - m);
    float lse = m + __logf(ss);
    float tl = predb[tok];
    const float* hrow = dhall + row*256;
    const float* wrow = predW + tok*256;
    #pragma unroll 4
    for (int k = 0; k < 256; ++k) tl += hrow[k] * wrow[k];
    if (tok != 0) { lsum = lse - tl; lcnt = 1.0f; }
  }
  rs[tid] = lsum; rc[tid] = lcnt;
  __syncthreads();
  for (int st = 128; st; st >>= 1) {
    if (tid < st) { rs[tid] += rs[tid + st]; rc[tid] += rc[tid + st]; }
    __syncthreads();
  }
  if (tid == 0) { lpart[blockIdx.x*2] = rs[0]; lpart[blockIdx.x*2 + 1] = rc[0]; }
}

// ---------- final: deterministic sum of 6 partials ----------
__global__ void k_loss_final(const float* __restrict__ lpart, float* __restrict__ out) {
  if (threadIdx.x == 0) {
    float s = 0.f, c = 0.f;
    for (int i = 0; i < 6; ++i) { s += lpart[i*2]; c += lpart[i*2 + 1]; }
    out[0] = s / fmaxf(c, 1.0f);
  }
}

// ---------- launch ----------
extern "C" void kernel_launch(void* const* d_in, const int* in_sizes, int n_in,
                              void* d_out, int out_size, void* d_ws, size_t ws_size,
                              hipStream_t stream) {
  const float* emb   = (const float*)d_in[0];
  const int* article = (const int*)d_in[1];
  const int* alen    = (const int*)d_in[2];
  const int* abstr   = (const int*)d_in[3];
  const float* eWihF = (const float*)d_in[4];
  const float* eWhhF = (const float*)d_in[5];
  const float* ebF   = (const float*)d_in[6];
  const float* eWihB = (const float*)d_in[7];
  const float* eWhhB = (const float*)d_in[8];
  const float* ebB   = (const float*)d_in[9];
  const float* dWih  = (const float*)d_in[10];
  const float* dWhh  = (const float*)d_in[11];
  const float* db    = (const float*)d_in[12];
  const float* pW    = (const float*)d_in[13];
  const float* pb    = (const float*)d_in[14];
  const float* asW   = (const float*)d_in[15];
  const float* asb   = (const float*)d_in[16];
  const float* ahW   = (const float*)d_in[17];
  const float* ahb   = (const float*)d_in[18];
  const float* afW   = (const float*)d_in[19];
  const float* afb   = (const float*)d_in[20];
  float* out = (float*)d_out;

  float* w = (float*)d_ws;
  size_t o = 0;
  float* xcomb  = w + o; o += (size_t)SS*NB*1024;
  float* encout = w + o; o += (size_t)NB*SS*HH;
  float* encwsR = w + o; o += (size_t)NB*SS*AA;
  float* decpre = w + o; o += (size_t)TT*NB*1024;
  float* dhall  = w + o; o += (size_t)TT*NB*HH;
  float* hpub   = w + o; o += NB*HH;
  float* cpub   = w + o; o += NB*8*272;
  float* wpub   = w + o; o += NB*8*72;
  float* c0buf  = w + o; o += NB*HH;
  float* pm     = w + o; o += (size_t)TT*NB*NCHUNK;
  float* ps     = w + o; o += (size_t)TT*NB*NCHUNK;
  float* lpart  = w + o; o += 16;
  int* flags = (int*)(w + o); o += 128;
  short* predWb = (short*)(w + o); o += (size_t)VVP*256/2;
  short* wfB    = (short*)(w + o); o += 512*1024/2;
  short* wbB    = (short*)(w + o); o += 512*1024/2;
  short* dwB    = (short*)(w + o); o += 1024*1024/2;

  k_init<<<1, 256, 0, stream>>>(flags);
  k_casts<<<512, 256, 0, stream>>>(eWihF, eWihB, dWih, wfB, wbB, dwB);
  k_embproj_enc_mfma<<<dim3(100, 4), 256, 0, stream>>>(emb, article, wfB, wbB, ebF, ebB, xcomb);
  k_encoder<<<256, 1024, 0, stream>>>(xcomb, eWhhF, eWhhB, encout, hpub, c0buf,
                                      pW, predWb, emb, abstr, dwB, db, decpre);
  k_encws<<<200, 256, 0, stream>>>(encout, asW, asb, encwsR);
  k_decoder<<<128, 1024, 0, stream>>>(decpre, dWhh, dWih, ahW, ahb, afW, afb,
                                      encwsR, encout, alen, c0buf, hpub, cpub, wpub, dhall, flags);
  k_pred_mfma<<<dim3(24, 120), 256, 0, stream>>>(dhall, predWb, pb, pm, ps);
  k_loss_part<<<6, 256, 0, stream>>>(pm, ps, dhall, pW, pb, abstr, lpart);
  k_loss_final<<<1, 64, 0, stream>>>(lpart, out);
}